// Round 1
// baseline (2164.629 us; speedup 1.0000x reference)
//
#include <hip/hip_runtime.h>
#include <hip/hip_bf16.h>

// DeepLSTM on MI355X — weight-stationary wavefront pipeline.
//
// Grid: 32 blocks x 512 threads. Block (l,g) = layer l (0..7), batch group g
// (0..3, 16 rows each). Weights live in VGPRs as bf16 MFMA fragments for the
// whole kernel; c-state in registers; h round-trips through LDS each step.
// Inter-layer handoff: 4-slot ring in d_ws + per-(l,g) progress flags
// (release-fence + relaxed store / relaxed poll + acquire-fence, agent scope).
// Back-pressure: producer polls consumer's flag before reusing a ring slot.
// Layer 7 fuses the output projection (waves 0..4) — no extra pipeline hop.
//
// ws layout: [0,4KB) flags (32 slots, 128B-strided to avoid false sharing),
//            [4KB, 4KB+512KB) ring: [L][G][4 slots][16][128] bf16.

#define T_ 512
#define L_ 8
#define H_ 128
#define G4_ 512
#define OUT_ 65
#define B_ 64
#define NG_ 4
#define BG_ 16
#define LDSW_ 136            // padded LDS row stride (bf16): 272B = 17*16B, keeps 16B align + bank spread
#define NSLOT_ 4
#define RSLOT_ (BG_ * H_)    // 2048 bf16 per ring slot
#define HT_OFF_ (B_ * T_ * OUT_)          // 2129920
#define CT_OFF_ (HT_OFF_ + L_ * B_ * H_)  // 2195456

typedef __bf16 bf16_t;
typedef bf16_t bf16x8 __attribute__((ext_vector_type(8)));
typedef bf16_t bf16x4 __attribute__((ext_vector_type(4)));
typedef float f32x4 __attribute__((ext_vector_type(4)));

__device__ __forceinline__ float sigm(float x) { return 1.f / (1.f + __expf(-x)); }
// overflow-safe tanh: never feeds expf a large positive arg (c can grow over 512 steps)
__device__ __forceinline__ float tanh_fast(float x) {
  float e = __expf(-2.f * fabsf(x));
  float r = (1.f - e) / (1.f + e);
  return copysignf(r, x);
}

__global__ void zero_flags(int* flags) { flags[threadIdx.x] = 0; }

__global__ __launch_bounds__(512, 2)  // 8 waves/block, 2 waves/EU -> VGPR cap 256 (need ~230)
void lstm_pipe(const int* __restrict__ xids, const float* __restrict__ embed,
               const float* __restrict__ wih_g, const float* __restrict__ bih_g,
               const float* __restrict__ whh_g, const float* __restrict__ bhh_g,
               const float* __restrict__ wout_g, const float* __restrict__ bout_g,
               float* __restrict__ out, int* __restrict__ flags,
               bf16_t* __restrict__ ring) {
  const int l    = blockIdx.x >> 2;
  const int g    = blockIdx.x & 3;
  const int tid  = threadIdx.x;
  const int wv   = tid >> 6;      // wave 0..7: owns gate col-tiles {wv, wv+8, wv+16, wv+24}
  const int lane = tid & 63;
  const int q    = lane >> 4;     // quad 0..3
  const int col  = lane & 15;

  __shared__ bf16_t h_lds[16 * LDSW_];  // own h_{t-1}, A-layout rows [m][k]
  __shared__ bf16_t xbuf[16 * LDSW_];   // layer-0 embedded input staging

  // ---- resident weight fragments (bf16, B-layout: lane holds B[k][n], n=col) ----
  bf16x8 wih[4][4], whh[4][4];  // [gate-class c][k-tile kt]
#pragma unroll
  for (int c = 0; c < 4; ++c) {
    const int n = wv * 16 + c * 128 + col;
#pragma unroll
    for (int kt = 0; kt < 4; ++kt) {
      bf16x8 a, b;
#pragma unroll
      for (int jj = 0; jj < 8; ++jj) {
        const int k = kt * 32 + q * 8 + jj;
        a[jj] = (bf16_t)wih_g[(l * H_ + k) * G4_ + n];
        b[jj] = (bf16_t)whh_g[(l * H_ + k) * G4_ + n];
      }
      wih[c][kt] = a;
      whh[c][kt] = b;
    }
  }
  float bias[4];
#pragma unroll
  for (int c = 0; c < 4; ++c) {
    const int n = wv * 16 + c * 128 + col;
    bias[c] = bih_g[l * G4_ + n] + bhh_g[l * G4_ + n];
  }
  // fused out-projection weights (layer 7, waves 0..4 cover n=0..79, masked to 65)
  bf16x8 wout[4];
  float bo = 0.f;
  const bool has_out = (l == L_ - 1) && (wv < 5);
  if (has_out) {
    const int n = wv * 16 + col;
#pragma unroll
    for (int kt = 0; kt < 4; ++kt) {
      bf16x8 a;
#pragma unroll
      for (int jj = 0; jj < 8; ++jj) {
        const int k = kt * 32 + q * 8 + jj;
        a[jj] = (n < OUT_) ? (bf16_t)wout_g[k * OUT_ + n] : (bf16_t)(0.f);
      }
      wout[kt] = a;
    }
    if (n < OUT_) bo = bout_g[n];
  }

  for (int i = tid; i < 16 * LDSW_; i += 512) h_lds[i] = (bf16_t)(0.f);
  float cst[4] = {0.f, 0.f, 0.f, 0.f};  // c-state: rows m=q*4+r, col j=16*wv+col
  __syncthreads();

  int* myflag   = flags + ((l * NG_ + g) << 5);
  int* prevflag = (l > 0) ? flags + (((l - 1) * NG_ + g) << 5) : flags;
  int* nextflag = (l < L_ - 1) ? flags + (((l + 1) * NG_ + g) << 5) : flags;
  bf16_t* myring        = ring + (l * NG_ + g) * NSLOT_ * RSLOT_;
  const bf16_t* srcring = (l > 0) ? ring + ((l - 1) * NG_ + g) * NSLOT_ * RSLOT_ : ring;

  const int aoff = col * LDSW_ + q * 8;  // A-fragment base: m=lane&15, k=q*8+j

#pragma unroll 1
  for (int t = 0; t < T_; ++t) {
    f32x4 acc[4];
#pragma unroll
    for (int c = 0; c < 4; ++c) acc[c] = (f32x4){0.f, 0.f, 0.f, 0.f};

    // ---- recurrent half first: overlaps with waiting on the producer ----
    bf16x8 ha[4];
#pragma unroll
    for (int kt = 0; kt < 4; ++kt)
      ha[kt] = *(const bf16x8*)(h_lds + aoff + kt * 32);
#pragma unroll
    for (int c = 0; c < 4; ++c)
#pragma unroll
      for (int kt = 0; kt < 4; ++kt)
        acc[c] = __builtin_amdgcn_mfma_f32_16x16x32_bf16(ha[kt], whh[c][kt], acc[c], 0, 0, 0);

    // ---- input half ----
    bf16x8 xa[4];
    if (l == 0) {
      __syncthreads();  // prior iter's xbuf readers done
      {
        const int m  = tid >> 5;
        const int c4 = (tid & 31) << 2;
        const int token = xids[(g * BG_ + m) * T_ + t];
        const float4 e = *(const float4*)(embed + token * H_ + c4);
        bf16x4 v;
        v[0] = (bf16_t)e.x; v[1] = (bf16_t)e.y; v[2] = (bf16_t)e.z; v[3] = (bf16_t)e.w;
        *(bf16x4*)(xbuf + m * LDSW_ + c4) = v;
      }
      __syncthreads();
#pragma unroll
      for (int kt = 0; kt < 4; ++kt)
        xa[kt] = *(const bf16x8*)(xbuf + aoff + kt * 32);
    } else {
      const int target = t + 1;
      while (__hip_atomic_load(prevflag, __ATOMIC_RELAXED, __HIP_MEMORY_SCOPE_AGENT) < target) {}
      __builtin_amdgcn_fence(__ATOMIC_ACQUIRE, "agent");
      const bf16_t* src = srcring + (t & (NSLOT_ - 1)) * RSLOT_;
#pragma unroll
      for (int kt = 0; kt < 4; ++kt)
        xa[kt] = *(const bf16x8*)(src + col * H_ + kt * 32 + q * 8);
    }
#pragma unroll
    for (int c = 0; c < 4; ++c)
#pragma unroll
      for (int kt = 0; kt < 4; ++kt)
        acc[c] = __builtin_amdgcn_mfma_f32_16x16x32_bf16(xa[kt], wih[c][kt], acc[c], 0, 0, 0);

    // ---- cell update: same lane holds i/f/g/o for its 4 (m,j) pairs ----
    float hv[4];
    bf16_t hb[4];
#pragma unroll
    for (int r = 0; r < 4; ++r) {
      const float iv = sigm(acc[0][r] + bias[0]);
      const float fv = sigm(acc[1][r] + bias[1]);
      const float gv = tanh_fast(acc[2][r] + bias[2]);
      const float ov = sigm(acc[3][r] + bias[3]);
      const float cv = fv * cst[r] + iv * gv;
      cst[r] = cv;
      const float h = ov * tanh_fast(cv);
      hv[r] = h;
      hb[r] = (bf16_t)h;
    }

    // back-pressure: don't overwrite a ring slot the consumer hasn't read
    if (l < L_ - 1 && t >= NSLOT_) {
      const int need = t - (NSLOT_ - 1);
      while (__hip_atomic_load(nextflag, __ATOMIC_RELAXED, __HIP_MEMORY_SCOPE_AGENT) < need) {}
    }

    __syncthreads();  // all waves done reading h_lds (h_{t-1})
    {
      const int jc = wv * 16 + col;
#pragma unroll
      for (int r = 0; r < 4; ++r)
        h_lds[(q * 4 + r) * LDSW_ + jc] = hb[r];
      if (l < L_ - 1) {
        bf16_t* dst = myring + (t & (NSLOT_ - 1)) * RSLOT_;
#pragma unroll
        for (int r = 0; r < 4; ++r)
          dst[(q * 4 + r) * H_ + jc] = hb[r];
      }
    }
    __syncthreads();  // implicit vmcnt(0): ring stores are in L2 before the fence below

    if (tid == 0) {
      if (l < L_ - 1) __builtin_amdgcn_fence(__ATOMIC_RELEASE, "agent");  // flush XCD L2 -> visible
      __hip_atomic_store(myflag, t + 1, __ATOMIC_RELAXED, __HIP_MEMORY_SCOPE_AGENT);
    }

    // ---- fused output projection (layer 7) ----
    if (has_out) {
      f32x4 oacc = (f32x4){0.f, 0.f, 0.f, 0.f};
#pragma unroll
      for (int kt = 0; kt < 4; ++kt) {
        const bf16x8 a = *(const bf16x8*)(h_lds + aoff + kt * 32);  // h_t, post-barrier
        oacc = __builtin_amdgcn_mfma_f32_16x16x32_bf16(a, wout[kt], oacc, 0, 0, 0);
      }
      const int n = wv * 16 + col;
      if (n < OUT_) {
#pragma unroll
        for (int r = 0; r < 4; ++r) {
          const int b = g * BG_ + q * 4 + r;
          out[(b * T_ + t) * OUT_ + n] = oacc[r] + bo;
        }
      }
    }

    if (t == T_ - 1) {  // final hT / cT (fp32 from registers)
      const int jc = wv * 16 + col;
#pragma unroll
      for (int r = 0; r < 4; ++r) {
        const int b = g * BG_ + q * 4 + r;
        out[HT_OFF_ + (l * B_ + b) * H_ + jc] = hv[r];
        out[CT_OFF_ + (l * B_ + b) * H_ + jc] = cst[r];
      }
    }
  }
}

extern "C" void kernel_launch(void* const* d_in, const int* in_sizes, int n_in,
                              void* d_out, int out_size, void* d_ws, size_t ws_size,
                              hipStream_t stream) {
  (void)in_sizes; (void)n_in; (void)out_size; (void)ws_size;
  const int*   x     = (const int*)d_in[0];
  const float* embed = (const float*)d_in[1];
  const float* w_ih  = (const float*)d_in[2];
  const float* b_ih  = (const float*)d_in[3];
  const float* w_hh  = (const float*)d_in[4];
  const float* b_hh  = (const float*)d_in[5];
  const float* w_out = (const float*)d_in[6];
  const float* b_out = (const float*)d_in[7];
  float* out = (float*)d_out;

  int* flags   = (int*)d_ws;                       // 4 KB (32 slots x 128B)
  bf16_t* ring = (bf16_t*)((char*)d_ws + 4096);    // 512 KB

  hipLaunchKernelGGL(zero_flags, dim3(1), dim3(1024), 0, stream, flags);
  hipLaunchKernelGGL(lstm_pipe, dim3(L_ * NG_), dim3(512), 0, stream,
                     x, embed, w_ih, b_ih, w_hh, b_hh, w_out, b_out,
                     out, flags, ring);
}

// Round 3
// 2058.496 us; speedup vs baseline: 1.0516x; 1.0516x over previous
//
#include <hip/hip_runtime.h>
#include <hip/hip_bf16.h>

// DeepLSTM on MI355X — weight-stationary wavefront pipeline, v3.
//
// v2 -> v3: DEADLOCK FIX. v2 gated the progress-flag store on l < L-1, so
// layer 7 never published and layer 6's ring back-pressure spun forever at
// t >= NSLOT. Flag publication is now unconditional (layer 7's store is
// cheap and is exactly what layer 6's back-pressure polls).
//
// v1 -> v2 recap: removed ALL agent-scope fences (buffer_wbl2/buffer_inv were
// 70 GB L2 writeback + 40 GB refetch per dispatch). Cross-block traffic uses
// agent-scope RELAXED atomics (sc1 => bypass non-coherent XCD L2, coherent at
// Infinity Cache). Ordering rides the s_waitcnt vmcnt(0) the compiler emits
// before every s_barrier: flag=t published after the barrier that drained the
// step t-1 ring stores. Monotonic flags register-cached so polls amortize to
// ~1/NSLOT steps. Layer-0 embed staging double-buffered.
//
// Grid: 32 blocks x 512 threads. Block (l,g) = layer l (0..7), batch group g
// (0..3, 16 rows each). Weights resident in VGPRs as bf16 MFMA fragments;
// c-state in registers; h round-trips through LDS each step. Layer 7 fuses
// the output projection.
//
// ws layout: [0,4KB) flags (32 slots, 128B-strided),
//            [4KB, ...) ring: [L][G][NSLOT][16][128] bf16.

#define T_ 512
#define L_ 8
#define H_ 128
#define G4_ 512
#define OUT_ 65
#define B_ 64
#define NG_ 4
#define BG_ 16
#define LDSW_ 136            // padded LDS row stride (bf16)
#define RSLOT_ (BG_ * H_)    // 2048 bf16 per ring slot = 512 u64
#define HT_OFF_ (B_ * T_ * OUT_)          // 2129920
#define CT_OFF_ (HT_OFF_ + L_ * B_ * H_)  // 2195456

typedef __bf16 bf16_t;
typedef bf16_t bf16x8 __attribute__((ext_vector_type(8)));
typedef bf16_t bf16x4 __attribute__((ext_vector_type(4)));
typedef float f32x4 __attribute__((ext_vector_type(4)));
typedef unsigned long long u64;

__device__ __forceinline__ float sigm(float x) { return 1.f / (1.f + __expf(-x)); }
// overflow-safe tanh (c can grow over 512 steps)
__device__ __forceinline__ float tanh_fast(float x) {
  float e = __expf(-2.f * fabsf(x));
  float r = (1.f - e) / (1.f + e);
  return copysignf(r, x);
}

__device__ __forceinline__ int flag_ld(int* p) {
  return __hip_atomic_load(p, __ATOMIC_RELAXED, __HIP_MEMORY_SCOPE_AGENT);
}
__device__ __forceinline__ void flag_st(int* p, int v) {
  __hip_atomic_store(p, v, __ATOMIC_RELAXED, __HIP_MEMORY_SCOPE_AGENT);
}
__device__ __forceinline__ u64 ring_ld(u64* p) {
  return __hip_atomic_load(p, __ATOMIC_RELAXED, __HIP_MEMORY_SCOPE_AGENT);
}
__device__ __forceinline__ void ring_st(u64* p, u64 v) {
  __hip_atomic_store(p, v, __ATOMIC_RELAXED, __HIP_MEMORY_SCOPE_AGENT);
}

__global__ void zero_flags(int* flags) { flags[threadIdx.x] = 0; }

template <int NSLOT>
__global__ __launch_bounds__(512, 2)  // 8 waves/block, 2 waves/EU (unified VGPR+AGPR budget 256)
void lstm_pipe(const int* __restrict__ xids, const float* __restrict__ embed,
               const float* __restrict__ wih_g, const float* __restrict__ bih_g,
               const float* __restrict__ whh_g, const float* __restrict__ bhh_g,
               const float* __restrict__ wout_g, const float* __restrict__ bout_g,
               float* __restrict__ out, int* __restrict__ flags,
               u64* __restrict__ ring) {
  const int l    = blockIdx.x >> 2;
  const int g    = blockIdx.x & 3;
  const int tid  = threadIdx.x;
  const int wv   = tid >> 6;      // wave 0..7: gate col-tiles {wv, wv+8, wv+16, wv+24}
  const int lane = tid & 63;
  const int q    = lane >> 4;     // quad 0..3
  const int col  = lane & 15;

  __shared__ bf16_t h_lds[16 * LDSW_];     // own h_{t-1}, A-layout [m][k]
  __shared__ bf16_t xbuf[2][16 * LDSW_];   // layer-0 embedded input, double-buffered

  // ---- resident weight fragments (bf16, B-layout: lane holds B[k][n], n=col) ----
  bf16x8 wih[4][4], whh[4][4];  // [gate-class c][k-tile kt]
#pragma unroll
  for (int c = 0; c < 4; ++c) {
    const int n = wv * 16 + c * 128 + col;
#pragma unroll
    for (int kt = 0; kt < 4; ++kt) {
      bf16x8 a, b;
#pragma unroll
      for (int jj = 0; jj < 8; ++jj) {
        const int k = kt * 32 + q * 8 + jj;
        a[jj] = (bf16_t)wih_g[(l * H_ + k) * G4_ + n];
        b[jj] = (bf16_t)whh_g[(l * H_ + k) * G4_ + n];
      }
      wih[c][kt] = a;
      whh[c][kt] = b;
    }
  }
  float bias[4];
#pragma unroll
  for (int c = 0; c < 4; ++c) {
    const int n = wv * 16 + c * 128 + col;
    bias[c] = bih_g[l * G4_ + n] + bhh_g[l * G4_ + n];
  }
  // fused out-projection weights (layer 7, waves 0..4 cover n=0..79, masked to 65)
  bf16x8 wout[4];
  float bo = 0.f;
  const bool has_out = (l == L_ - 1) && (wv < 5);
  if (has_out) {
    const int n = wv * 16 + col;
#pragma unroll
    for (int kt = 0; kt < 4; ++kt) {
      bf16x8 a;
#pragma unroll
      for (int jj = 0; jj < 8; ++jj) {
        const int k = kt * 32 + q * 8 + jj;
        a[jj] = (n < OUT_) ? (bf16_t)wout_g[k * OUT_ + n] : (bf16_t)(0.f);
      }
      wout[kt] = a;
    }
    if (n < OUT_) bo = bout_g[n];
  }

  for (int i = tid; i < 16 * LDSW_; i += 512) h_lds[i] = (bf16_t)(0.f);
  // layer-0 prologue: stage xbuf[0] for t=0
  if (l == 0) {
    const int m  = tid >> 5;
    const int c4 = (tid & 31) << 2;
    const int token = xids[(g * BG_ + m) * T_ + 0];
    const float4 e = *(const float4*)(embed + token * H_ + c4);
    bf16x4 v;
    v[0] = (bf16_t)e.x; v[1] = (bf16_t)e.y; v[2] = (bf16_t)e.z; v[3] = (bf16_t)e.w;
    *(bf16x4*)(&xbuf[0][m * LDSW_ + c4]) = v;
  }
  float cst[4] = {0.f, 0.f, 0.f, 0.f};  // c-state: rows m=q*4+r, col j=16*wv+col
  __syncthreads();

  int* myflag   = flags + ((l * NG_ + g) << 5);
  int* prevflag = (l > 0) ? flags + (((l - 1) * NG_ + g) << 5) : flags;
  int* nextflag = (l < L_ - 1) ? flags + (((l + 1) * NG_ + g) << 5) : flags;
  u64* myring  = ring + (size_t)(l * NG_ + g) * NSLOT * (RSLOT_ / 4);
  u64* srcring = (l > 0) ? ring + (size_t)((l - 1) * NG_ + g) * NSLOT * (RSLOT_ / 4) : ring;

  const int aoff = col * LDSW_ + q * 8;  // A-fragment base: m=lane&15, k=q*8+j
  int seen_prev = 0, seen_next = 0;      // register-cached monotonic flag values

#pragma unroll 1
  for (int t = 0; t < T_; ++t) {
    // ---- (A) acquire input fragments (issue ring loads early; latency overlaps (B)) ----
    bf16x8 xa[4];
    if (l == 0) {
#pragma unroll
      for (int kt = 0; kt < 4; ++kt)
        xa[kt] = *(const bf16x8*)(&xbuf[t & 1][aoff + kt * 32]);
    } else {
      const int target = t + 1;
      if (seen_prev < target) {
        int v;
        do { v = flag_ld(prevflag); } while (v < target);
        seen_prev = v;
      }
      __asm__ __volatile__("" ::: "memory");
      u64* src = srcring + (size_t)(t & (NSLOT - 1)) * (RSLOT_ / 4);
#pragma unroll
      for (int kt = 0; kt < 4; ++kt) {
        const int e0 = col * 32 + kt * 8 + q * 2;  // u64 index of (col*128 + kt*32 + q*8)
        union { u64 u[2]; bf16x8 v; } tmp;
        tmp.u[0] = ring_ld(src + e0);
        tmp.u[1] = ring_ld(src + e0 + 1);
        xa[kt] = tmp.v;
      }
    }

    // ---- (B) recurrent half ----
    f32x4 acc[4];
#pragma unroll
    for (int c = 0; c < 4; ++c) acc[c] = (f32x4){0.f, 0.f, 0.f, 0.f};
    bf16x8 ha[4];
#pragma unroll
    for (int kt = 0; kt < 4; ++kt)
      ha[kt] = *(const bf16x8*)(h_lds + aoff + kt * 32);
#pragma unroll
    for (int c = 0; c < 4; ++c)
#pragma unroll
      for (int kt = 0; kt < 4; ++kt)
        acc[c] = __builtin_amdgcn_mfma_f32_16x16x32_bf16(ha[kt], whh[c][kt], acc[c], 0, 0, 0);

    // ---- (C) input half ----
#pragma unroll
    for (int c = 0; c < 4; ++c)
#pragma unroll
      for (int kt = 0; kt < 4; ++kt)
        acc[c] = __builtin_amdgcn_mfma_f32_16x16x32_bf16(xa[kt], wih[c][kt], acc[c], 0, 0, 0);

    // ---- (D) cell update: same lane holds i/f/g/o for its 4 (m,j) pairs ----
    float hv[4];
    bf16_t hb[4];
#pragma unroll
    for (int r = 0; r < 4; ++r) {
      const float iv = sigm(acc[0][r] + bias[0]);
      const float fv = sigm(acc[1][r] + bias[1]);
      const float gv = tanh_fast(acc[2][r] + bias[2]);
      const float ov = sigm(acc[3][r] + bias[3]);
      const float cv = fv * cst[r] + iv * gv;
      cst[r] = cv;
      const float h = ov * tanh_fast(cv);
      hv[r] = h;
      hb[r] = (bf16_t)h;
    }

    // ---- (E) back-pressure: slot t%NSLOT overwrite needs consumer past step t-NSLOT ----
    if (l < L_ - 1 && t >= NSLOT) {
      const int need = t - NSLOT + 1;
      if (seen_next < need) {
        int v;
        do { v = flag_ld(nextflag); } while (v < need);
        seen_next = v;
      }
    }

    // ---- (F) barrier: drains (per compiler vmcnt(0) before s_barrier) ALL threads'
    //      step t-1 ring stores; also ends h_lds/xbuf read phase ----
    __syncthreads();
    if (tid == 0) {
      __asm__ __volatile__("" ::: "memory");
      flag_st(myflag, t);  // "ring data for steps <= t-1 is visible" (ALL layers publish)
    }

    // ---- (G) write h_t to LDS; layer 0 stages next token ----
    {
      const int jc = wv * 16 + col;
#pragma unroll
      for (int r = 0; r < 4; ++r)
        h_lds[(q * 4 + r) * LDSW_ + jc] = hb[r];
    }
    if (l == 0 && t + 1 < T_) {
      const int m  = tid >> 5;
      const int c4 = (tid & 31) << 2;
      const int token = xids[(g * BG_ + m) * T_ + (t + 1)];
      const float4 e = *(const float4*)(embed + token * H_ + c4);
      bf16x4 v;
      v[0] = (bf16_t)e.x; v[1] = (bf16_t)e.y; v[2] = (bf16_t)e.z; v[3] = (bf16_t)e.w;
      *(bf16x4*)(&xbuf[(t + 1) & 1][m * LDSW_ + c4]) = v;
    }
    // ---- (H) barrier: h_lds (and xbuf) ready ----
    __syncthreads();

    // ---- (I) ring store: one contiguous u64 per thread, straight from LDS ----
    if (l < L_ - 1) {
      const int m  = tid >> 5;
      const int c4 = (tid & 31) << 2;
      const u64 val = *(const u64*)(&h_lds[m * LDSW_ + c4]);
      ring_st(myring + (size_t)(t & (NSLOT - 1)) * (RSLOT_ / 4) + (m * 32 + (tid & 31)), val);
    }

    // ---- (J) fused output projection (layer 7) ----
    if (has_out) {
      f32x4 oacc = (f32x4){0.f, 0.f, 0.f, 0.f};
#pragma unroll
      for (int kt = 0; kt < 4; ++kt) {
        const bf16x8 a = *(const bf16x8*)(h_lds + aoff + kt * 32);  // h_t, post-barrier
        oacc = __builtin_amdgcn_mfma_f32_16x16x32_bf16(a, wout[kt], oacc, 0, 0, 0);
      }
      const int n = wv * 16 + col;
      if (n < OUT_) {
#pragma unroll
        for (int r = 0; r < 4; ++r) {
          const int b = g * BG_ + q * 4 + r;
          out[(b * T_ + t) * OUT_ + n] = oacc[r] + bo;
        }
      }
    }

    // ---- (K) final hT / cT ----
    if (t == T_ - 1) {
      const int jc = wv * 16 + col;
#pragma unroll
      for (int r = 0; r < 4; ++r) {
        const int b = g * BG_ + q * 4 + r;
        out[HT_OFF_ + (l * B_ + b) * H_ + jc] = hv[r];
        out[CT_OFF_ + (l * B_ + b) * H_ + jc] = cst[r];
      }
    }
  }

  // epilogue: publish completion of step T-1 (drained by this barrier)
  __syncthreads();
  if (tid == 0) flag_st(myflag, T_);
}

extern "C" void kernel_launch(void* const* d_in, const int* in_sizes, int n_in,
                              void* d_out, int out_size, void* d_ws, size_t ws_size,
                              hipStream_t stream) {
  (void)in_sizes; (void)n_in; (void)out_size;
  const int*   x     = (const int*)d_in[0];
  const float* embed = (const float*)d_in[1];
  const float* w_ih  = (const float*)d_in[2];
  const float* b_ih  = (const float*)d_in[3];
  const float* w_hh  = (const float*)d_in[4];
  const float* b_hh  = (const float*)d_in[5];
  const float* w_out = (const float*)d_in[6];
  const float* b_out = (const float*)d_in[7];
  float* out = (float*)d_out;

  int* flags = (int*)d_ws;                       // 4 KB (32 slots x 128B)
  u64* ring  = (u64*)((char*)d_ws + 4096);

  hipLaunchKernelGGL(zero_flags, dim3(1), dim3(1024), 0, stream, flags);

  const size_t need8 = 4096 + (size_t)32 * 8 * (RSLOT_ * 2);  // flags + 1 MB ring
  if (ws_size >= need8) {
    hipLaunchKernelGGL((lstm_pipe<8>), dim3(L_ * NG_), dim3(512), 0, stream,
                       x, embed, w_ih, b_ih, w_hh, b_hh, w_out, b_out, out, flags, ring);
  } else {
    hipLaunchKernelGGL((lstm_pipe<4>), dim3(L_ * NG_), dim3(512), 0, stream,
                       x, embed, w_ih, b_ih, w_hh, b_hh, w_out, b_out, out, flags, ring);
  }
}

// Round 4
// 1405.010 us; speedup vs baseline: 1.5407x; 1.4651x over previous
//
#include <hip/hip_runtime.h>
#include <hip/hip_bf16.h>

// DeepLSTM on MI355X — weight-stationary wavefront pipeline, v4: CHUNKED HANDOFF.
//
// v3 post-mortem: per-step cross-XCD chain (store->IC, flag->IC, poll
// quantization, uncached ring loads) ~ 4 x 2000 cyc serialized per step
// dominated (9400 cyc/step measured vs ~600 compute). Fences were ~free
// (v1 vs v3: 2115 vs 2058 us). Fix: amortize ALL cross-die sync over CT=8
// steps. Within a chunk the recurrence is LDS-local. Handoff = per-chunk:
// one release fence + one flag (producer), one poll (tid0) + one acquire
// fence + one bulk 32KB ring->LDS copy (consumer). Full-history ring when
// ws permits (no back-pressure at all); smaller power-of-2 rings otherwise.
//
// Grid: 32 blocks x 512 threads. Block (l,g) = layer l (0..7), batch group g
// (0..3, 16 rows). Weights resident as bf16 MFMA fragments; c-state in
// registers; h round-trips through LDS; layer 7 fuses the out-projection.
//
// ws: [0,8KB) flags (prod[32] @0, cons[32] @4KB, 128B stride),
//     [8KB,...) ring: [pair=l*4+g][RING_T][16][128] bf16 (producers l=0..6).

#define T_ 512
#define L_ 8
#define H_ 128
#define G4_ 512
#define OUT_ 65
#define B_ 64
#define NG_ 4
#define BG_ 16
#define LDSW_ 136                          // padded LDS row stride (bf16)
#define HT_OFF_ (B_ * T_ * OUT_)           // 2129920
#define CT_OFF_ (HT_OFF_ + L_ * B_ * H_)   // 2195456
#define STEP_U64_ 512                      // one step's h-tile: 16x128 bf16 = 4KB = 512 u64

typedef __bf16 bf16_t;
typedef bf16_t bf16x8 __attribute__((ext_vector_type(8)));
typedef bf16_t bf16x4 __attribute__((ext_vector_type(4)));
typedef float f32x4 __attribute__((ext_vector_type(4)));
typedef unsigned long long u64;

__device__ __forceinline__ float sigm(float x) { return 1.f / (1.f + __expf(-x)); }
__device__ __forceinline__ float tanh_fast(float x) {
  float e = __expf(-2.f * fabsf(x));
  float r = (1.f - e) / (1.f + e);
  return copysignf(r, x);
}

__device__ __forceinline__ int flag_ld(int* p) {
  return __hip_atomic_load(p, __ATOMIC_RELAXED, __HIP_MEMORY_SCOPE_AGENT);
}
__device__ __forceinline__ void flag_st(int* p, int v) {
  __hip_atomic_store(p, v, __ATOMIC_RELAXED, __HIP_MEMORY_SCOPE_AGENT);
}

__global__ void zero_flags(int* flags) { flags[blockIdx.x * 1024 + threadIdx.x] = 0; }

template <int CT, int RING_T>
__global__ __launch_bounds__(512, 2)
void lstm_pipe(const int* __restrict__ xids, const float* __restrict__ embed,
               const float* __restrict__ wih_g, const float* __restrict__ bih_g,
               const float* __restrict__ whh_g, const float* __restrict__ bhh_g,
               const float* __restrict__ wout_g, const float* __restrict__ bout_g,
               float* __restrict__ out, int* __restrict__ flags,
               u64* __restrict__ ring) {
  const int l    = blockIdx.x >> 2;
  const int g    = blockIdx.x & 3;
  const int tid  = threadIdx.x;
  const int wv   = tid >> 6;      // wave 0..7: gate col-tiles {wv, wv+8, wv+16, wv+24}
  const int lane = tid & 63;
  const int q    = lane >> 4;     // quad 0..3
  const int col  = lane & 15;

  __shared__ __align__(16) bf16_t h_lds[16 * LDSW_];          // h_{t-1}, A-layout [m][k]
  __shared__ __align__(16) bf16_t xchunk[CT * 16 * LDSW_];    // incoming chunk, A-layout

  // ---- resident weight fragments (bf16, B-layout: lane holds B[k][n], n=col) ----
  bf16x8 wih[4][4], whh[4][4];  // [gate-class c][k-tile kt]
#pragma unroll
  for (int c = 0; c < 4; ++c) {
    const int n = wv * 16 + c * 128 + col;
#pragma unroll
    for (int kt = 0; kt < 4; ++kt) {
      bf16x8 a, b;
#pragma unroll
      for (int jj = 0; jj < 8; ++jj) {
        const int k = kt * 32 + q * 8 + jj;
        a[jj] = (bf16_t)wih_g[(l * H_ + k) * G4_ + n];
        b[jj] = (bf16_t)whh_g[(l * H_ + k) * G4_ + n];
      }
      wih[c][kt] = a;
      whh[c][kt] = b;
    }
  }
  float bias[4];
#pragma unroll
  for (int c = 0; c < 4; ++c) {
    const int n = wv * 16 + c * 128 + col;
    bias[c] = bih_g[l * G4_ + n] + bhh_g[l * G4_ + n];
  }
  bf16x8 wout[4];
  float bo = 0.f;
  const bool has_out = (l == L_ - 1) && (wv < 5);
  if (has_out) {
    const int n = wv * 16 + col;
#pragma unroll
    for (int kt = 0; kt < 4; ++kt) {
      bf16x8 a;
#pragma unroll
      for (int jj = 0; jj < 8; ++jj) {
        const int k = kt * 32 + q * 8 + jj;
        a[jj] = (n < OUT_) ? (bf16_t)wout_g[k * OUT_ + n] : (bf16_t)(0.f);
      }
      wout[kt] = a;
    }
    if (n < OUT_) bo = bout_g[n];
  }

  for (int i = tid; i < 16 * LDSW_; i += 512) h_lds[i] = (bf16_t)(0.f);
  float cst[4] = {0.f, 0.f, 0.f, 0.f};
  __syncthreads();

  int* myprod   = flags + ((l * NG_ + g) << 5);
  int* prevprod = (l > 0) ? flags + (((l - 1) * NG_ + g) << 5) : flags;
  int* mycons   = flags + 1024 + ((l * NG_ + g) << 5);
  int* nextcons = (l < L_ - 1) ? flags + 1024 + (((l + 1) * NG_ + g) << 5) : flags;
  u64* myring  = (l < L_ - 1) ? ring + (size_t)(l * NG_ + g) * RING_T * STEP_U64_ : ring;
  const u64* srcring = (l > 0) ? ring + (size_t)((l - 1) * NG_ + g) * RING_T * STEP_U64_ : ring;

  const int aoff = col * LDSW_ + q * 8;  // A-fragment: m=lane&15, k=q*8+j
  int seen_prod = 0, seen_cons = 0;      // tid0-only cached monotonic flag values

#pragma unroll 1
  for (int ch = 0; ch < T_ / CT; ++ch) {
    const int t0 = ch * CT;

    // ================= chunk input acquire =================
    if (l == 0) {
      // gather embed -> xchunk (bf16, A-layout rows)
      const int m  = tid >> 5;
      const int c4 = (tid & 31) << 2;
#pragma unroll
      for (int tl = 0; tl < CT; ++tl) {
        const int token = xids[(g * BG_ + m) * T_ + t0 + tl];
        const float4 e = *(const float4*)(embed + token * H_ + c4);
        bf16x4 v;
        v[0] = (bf16_t)e.x; v[1] = (bf16_t)e.y; v[2] = (bf16_t)e.z; v[3] = (bf16_t)e.w;
        *(bf16x4*)(&xchunk[(tl * 16 + m) * LDSW_ + c4]) = v;
      }
    } else {
      if (tid == 0) {
        const int target = t0 + CT;
        if (seen_prod < target) {
          int v;
          do { v = flag_ld(prevprod); } while (v < target);
          seen_prod = v;
        }
      }
      __syncthreads();
      __builtin_amdgcn_fence(__ATOMIC_ACQUIRE, "agent");
      // bulk copy ring chunk -> xchunk (CT*16 rows x 256B)
      const int idx = tid >> 2;            // row id
      if (idx < CT * 16) {
        const int tl = idx >> 4, m = idx & 15, seg = tid & 3;
        const u64* src = srcring + (size_t)((t0 + tl) & (RING_T - 1)) * STEP_U64_ + m * 32 + seg * 8;
        bf16_t* dst = &xchunk[(tl * 16 + m) * LDSW_ + seg * 32];
#pragma unroll
        for (int j = 0; j < 4; ++j) {
          const uint4 vv = *(const uint4*)(src + j * 2);
          *(uint4*)(dst + j * 8) = vv;
        }
      }
    }
    __syncthreads();  // xchunk ready; consumer copy loads drained (vmcnt at barrier)

    if (RING_T < T_) {
      if (l > 0 && tid == 0) flag_st(mycons, t0 + CT);  // consumed through t0+CT
      if (l < L_ - 1 && t0 + CT > RING_T) {             // slot-reuse back-pressure
        if (tid == 0) {
          const int need = t0 + CT - RING_T;
          if (seen_cons < need) {
            int v;
            do { v = flag_ld(nextcons); } while (v < need);
            seen_cons = v;
          }
        }
        __syncthreads();
      }
    }

    // ================= CT recurrent steps (all LDS-local) =================
#pragma unroll 1
    for (int tl = 0; tl < CT; ++tl) {
      const int t = t0 + tl;

      f32x4 acc[4];
#pragma unroll
      for (int c = 0; c < 4; ++c) acc[c] = (f32x4){0.f, 0.f, 0.f, 0.f};

      bf16x8 xa[4], ha[4];
      const int xoff = (tl * 16 + col) * LDSW_ + q * 8;
#pragma unroll
      for (int kt = 0; kt < 4; ++kt) {
        xa[kt] = *(const bf16x8*)(&xchunk[xoff + kt * 32]);
        ha[kt] = *(const bf16x8*)(h_lds + aoff + kt * 32);
      }
#pragma unroll
      for (int c = 0; c < 4; ++c)
#pragma unroll
        for (int kt = 0; kt < 4; ++kt)
          acc[c] = __builtin_amdgcn_mfma_f32_16x16x32_bf16(ha[kt], whh[c][kt], acc[c], 0, 0, 0);
#pragma unroll
      for (int c = 0; c < 4; ++c)
#pragma unroll
        for (int kt = 0; kt < 4; ++kt)
          acc[c] = __builtin_amdgcn_mfma_f32_16x16x32_bf16(xa[kt], wih[c][kt], acc[c], 0, 0, 0);

      float hv[4];
      bf16_t hb[4];
#pragma unroll
      for (int r = 0; r < 4; ++r) {
        const float iv = sigm(acc[0][r] + bias[0]);
        const float fv = sigm(acc[1][r] + bias[1]);
        const float gv = tanh_fast(acc[2][r] + bias[2]);
        const float ov = sigm(acc[3][r] + bias[3]);
        const float cv = fv * cst[r] + iv * gv;
        cst[r] = cv;
        const float h = ov * tanh_fast(cv);
        hv[r] = h;
        hb[r] = (bf16_t)h;
      }

      __syncthreads();  // end h_{t-1} read phase
      {
        const int jc = wv * 16 + col;
#pragma unroll
        for (int r = 0; r < 4; ++r)
          h_lds[(q * 4 + r) * LDSW_ + jc] = hb[r];
      }
      __syncthreads();  // h_t ready in LDS

      // plain coalesced ring store of h_t (visibility deferred to chunk fence)
      if (l < L_ - 1) {
        const u64 val = *(const u64*)(&h_lds[(tid >> 5) * LDSW_ + ((tid & 31) << 2)]);
        myring[(size_t)(t & (RING_T - 1)) * STEP_U64_ + tid] = val;
      }

      // fused output projection (layer 7)
      if (has_out) {
        f32x4 oacc = (f32x4){0.f, 0.f, 0.f, 0.f};
#pragma unroll
        for (int kt = 0; kt < 4; ++kt) {
          const bf16x8 a = *(const bf16x8*)(h_lds + aoff + kt * 32);
          oacc = __builtin_amdgcn_mfma_f32_16x16x32_bf16(a, wout[kt], oacc, 0, 0, 0);
        }
        const int n = wv * 16 + col;
        if (n < OUT_) {
#pragma unroll
          for (int r = 0; r < 4; ++r) {
            const int b = g * BG_ + q * 4 + r;
            out[(b * T_ + t) * OUT_ + n] = oacc[r] + bo;
          }
        }
      }

      if (t == T_ - 1) {  // final hT / cT
        const int jc = wv * 16 + col;
#pragma unroll
        for (int r = 0; r < 4; ++r) {
          const int b = g * BG_ + q * 4 + r;
          out[HT_OFF_ + (l * B_ + b) * H_ + jc] = hv[r];
          out[CT_OFF_ + (l * B_ + b) * H_ + jc] = cst[r];
        }
      }
    }

    // ================= chunk publish (producers) =================
    if (l < L_ - 1) {
      __syncthreads();  // vmcnt(0) drain: all threads' ring stores in L2
      if (tid == 0) {
        __builtin_amdgcn_fence(__ATOMIC_RELEASE, "agent");  // L2 -> IC
        flag_st(myprod, t0 + CT);
      }
    }
  }
}

extern "C" void kernel_launch(void* const* d_in, const int* in_sizes, int n_in,
                              void* d_out, int out_size, void* d_ws, size_t ws_size,
                              hipStream_t stream) {
  (void)in_sizes; (void)n_in; (void)out_size;
  const int*   x     = (const int*)d_in[0];
  const float* embed = (const float*)d_in[1];
  const float* w_ih  = (const float*)d_in[2];
  const float* b_ih  = (const float*)d_in[3];
  const float* w_hh  = (const float*)d_in[4];
  const float* b_hh  = (const float*)d_in[5];
  const float* w_out = (const float*)d_in[6];
  const float* b_out = (const float*)d_in[7];
  float* out = (float*)d_out;

  int* flags = (int*)d_ws;                     // 8 KB: prod[32]@0, cons[32]@4KB
  u64* ring  = (u64*)((char*)d_ws + 8192);

  hipLaunchKernelGGL(zero_flags, dim3(2), dim3(1024), 0, stream, flags);

  const size_t base = 8192;
  const size_t ring_bytes_per_pair_step = 4096;  // 16x128 bf16
  auto need = [&](int ring_t) { return base + (size_t)28 * ring_t * ring_bytes_per_pair_step; };

  if (ws_size >= need(512)) {        // 56 MB: full history, no back-pressure
    hipLaunchKernelGGL((lstm_pipe<8, 512>), dim3(L_ * NG_), dim3(512), 0, stream,
                       x, embed, w_ih, b_ih, w_hh, b_hh, w_out, b_out, out, flags, ring);
  } else if (ws_size >= need(16)) {  // 1.8 MB
    hipLaunchKernelGGL((lstm_pipe<8, 16>), dim3(L_ * NG_), dim3(512), 0, stream,
                       x, embed, w_ih, b_ih, w_hh, b_hh, w_out, b_out, out, flags, ring);
  } else if (ws_size >= need(8)) {   // 0.92 MB
    hipLaunchKernelGGL((lstm_pipe<8, 8>), dim3(L_ * NG_), dim3(512), 0, stream,
                       x, embed, w_ih, b_ih, w_hh, b_hh, w_out, b_out, out, flags, ring);
  } else {                           // 0.47 MB worst case
    hipLaunchKernelGGL((lstm_pipe<4, 4>), dim3(L_ * NG_), dim3(512), 0, stream,
                       x, embed, w_ih, b_ih, w_hh, b_hh, w_out, b_out, out, flags, ring);
  }
}